// Round 1
// baseline (1254.927 us; speedup 1.0000x reference)
//
#include <hip/hip_runtime.h>
#include <hip/hip_bf16.h>

// Viterbi CRF decode: B=512, T=512, K=64 (K == wavefront size).
// Kernel 1 (forward): 1 wave per batch. Lane j owns tag j. trans column j in
//   64 VGPRs; score broadcast via LDS float4 reads; 4 blocked argmax chains
//   (strict-greater, ascending merge) reproduce jnp.argmax first-index ties.
//   cand = (score_i + trans_ij) + emit_j  -- exact reference fp association,
//   so scores are bitwise identical to the reference scan.
// Kernel 2 (backtrace): per-batch wave; lane l holds hist[r][l]; dependent
//   chain hops via __shfl(row, tag) (~LDS latency, not global-load latency).
// Workspace: hist uint8 [B][512][K] = 16.78 MB (row 511 unused pad) +
//   best_last int[B].

#define TT 512
#define BB 512
#define KK 64

__global__ __launch_bounds__(64) void viterbi_fwd(
    const float* __restrict__ emissions,   // [B,T,K]
    const int* __restrict__ attn_mask,     // [B,T]
    const float* __restrict__ start_t,     // [K]
    const float* __restrict__ end_t,       // [K]
    const float* __restrict__ trans,       // [K,K]
    unsigned char* __restrict__ hist,      // [B,512,K] (row 511 pad)
    int* __restrict__ best_last)           // [B]
{
    const int b = blockIdx.x;
    const int j = threadIdx.x;
    __shared__ __align__(16) float s_score[KK];

    // trans column j into registers: tc[i] = trans[i][j]
    float tc[KK];
#pragma unroll
    for (int i = 0; i < KK; ++i) tc[i] = trans[i * KK + j];

    const float* eb = emissions + (size_t)b * TT * KK;
    const int* mb = attn_mask + (size_t)b * TT;
    unsigned char* hb = hist + (size_t)b * TT * KK;

    float score = start_t[j] + eb[j];

    // 2-deep prefetch rings for emissions and mask
    float e0 = eb[1 * KK + j];
    float e1 = eb[2 * KK + j];
    int m0 = mb[1];
    int m1 = mb[2];

    for (int t = 1; t < TT; ++t) {
        __syncthreads();
        s_score[j] = score;
        __syncthreads();

        float e = e0; e0 = e1;
        int m = m0; m0 = m1;
        int tn = (t + 2 < TT) ? (t + 2) : (TT - 1);
        e1 = eb[(size_t)tn * KK + j];
        m1 = mb[tn];

        float bb_[4];
        int ii_[4];
#pragma unroll
        for (int c = 0; c < 4; ++c) { bb_[c] = -3.402823466e38f; ii_[c] = c * 16; }

        const float4* sp = (const float4*)s_score;
#pragma unroll
        for (int g = 0; g < 4; ++g) {
#pragma unroll
            for (int c = 0; c < 4; ++c) {
                float4 v = sp[c * 4 + g];
#define VSTEP(comp, qq)                                                        \
                {                                                              \
                    const int iidx = c * 16 + g * 4 + qq;                      \
                    float cand = (comp + tc[iidx]) + e;                        \
                    if (cand > bb_[c]) { bb_[c] = cand; ii_[c] = iidx; }       \
                }
                VSTEP(v.x, 0)
                VSTEP(v.y, 1)
                VSTEP(v.z, 2)
                VSTEP(v.w, 3)
#undef VSTEP
            }
        }
        // merge chains ascending (strict > keeps earliest index on ties)
        float best = bb_[0]; int bi = ii_[0];
        if (bb_[1] > best) { best = bb_[1]; bi = ii_[1]; }
        if (bb_[2] > best) { best = bb_[2]; bi = ii_[2]; }
        if (bb_[3] > best) { best = bb_[3]; bi = ii_[3]; }

        hb[(size_t)(t - 1) * KK + j] = (unsigned char)bi;
        score = m ? best : score;   // freeze past sequence end
    }

    float fin = score + end_t[j];
    __syncthreads();
    s_score[j] = fin;
    __syncthreads();
    if (j == 0) {
        float bv = s_score[0]; int bt = 0;
#pragma unroll
        for (int k = 1; k < KK; ++k) {
            if (s_score[k] > bv) { bv = s_score[k]; bt = k; }
        }
        best_last[b] = bt;
    }
}

__global__ __launch_bounds__(64) void viterbi_bt(
    const unsigned char* __restrict__ hist,  // [B,512,K]
    const int* __restrict__ attn_mask,       // [B,T]
    const int* __restrict__ best_last,       // [B]
    int* __restrict__ out)                   // [B,T] int32
{
    const int b = blockIdx.x;
    const int l = threadIdx.x;
    __shared__ int path[TT];

    const unsigned char* hb = hist + (size_t)b * TT * KK;
    const int* mb = attn_mask + (size_t)b * TT;

    int tag = best_last[b];
    if (l == 0) path[TT - 1] = tag;

    for (int k = 7; k >= 0; --k) {
        const int base = k * 64;
        // lane l holds hist[r][l] for rows r = base..base+63 (row 511 clamped/unused)
        int rows[64];
#pragma unroll
        for (int i = 0; i < 64; ++i) {
            int r = base + i;
            int rr = (r < TT - 1) ? r : 0;
            rows[i] = hb[(size_t)rr * KK + l];
        }
        int midx = base + l + 1;
        if (midx > TT - 1) midx = TT - 1;
        int mreg = mb[midx];   // lane l holds mask[b][base+l+1]

#pragma unroll
        for (int i = 63; i >= 0; --i) {
            int r = base + i;
            if (r < TT - 1) {
                int p = __shfl(rows[i], tag);
                int m = __shfl(mreg, i);
                tag = m ? p : tag;
                if (l == 0) path[r] = tag;
            }
        }
    }
    __syncthreads();
#pragma unroll
    for (int c = 0; c < 8; ++c) {
        out[(size_t)b * TT + c * 64 + l] = path[c * 64 + l];
    }
}

extern "C" void kernel_launch(void* const* d_in, const int* in_sizes, int n_in,
                              void* d_out, int out_size, void* d_ws, size_t ws_size,
                              hipStream_t stream) {
    const float* emissions = (const float*)d_in[0];
    const int* attn_mask   = (const int*)d_in[1];
    const float* start_t   = (const float*)d_in[2];
    const float* end_t     = (const float*)d_in[3];
    const float* trans     = (const float*)d_in[4];
    int* out = (int*)d_out;

    unsigned char* hist = (unsigned char*)d_ws;
    int* best_last = (int*)((char*)d_ws + (size_t)BB * TT * KK);

    viterbi_fwd<<<BB, KK, 0, stream>>>(emissions, attn_mask, start_t, end_t,
                                       trans, hist, best_last);
    viterbi_bt<<<BB, KK, 0, stream>>>(hist, attn_mask, best_last, out);
}

// Round 2
// 464.758 us; speedup vs baseline: 2.7002x; 2.7002x over previous
//
#include <hip/hip_runtime.h>
#include <hip/hip_bf16.h>

// Viterbi CRF decode: B=512, T=512, K=64.
// Round 2: forward uses 4 waves/block (256 thr). Wave w owns prev-tags
// i in [16w,16w+16). Score broadcast via v_readlane (SGPR fold into v_add)
// instead of LDS; per-step cross-wave merge through a small double-buffered
// LDS exchange (1 barrier/step). fp association (score+trans)+emit kept
// exactly -> bitwise-identical scores to reference; strict-> chains merged
// in ascending index order reproduce jnp.argmax first-index tie-break.
// Backtrace: coalesced dword row loads (4 rows per wave-load), 2-chunk
// software pipeline, shfl+byte-extract dependent chain.
// Workspace: hist uint8 [B][512][K] = 16.78 MB (row 511 pad) + best_last[B].

#define TT 512
#define BB 512
#define KK 64
#define NW 4    // waves per block (forward)
#define IW 16   // prev-tags per wave

#define NEG_INF (-3.402823466e38f)

__global__ __launch_bounds__(256) void viterbi_fwd(
    const float* __restrict__ emissions,   // [B,T,K]
    const int* __restrict__ attn_mask,     // [B,T]
    const float* __restrict__ start_t,     // [K]
    const float* __restrict__ end_t,       // [K]
    const float* __restrict__ trans,       // [K,K]
    unsigned char* __restrict__ hist,      // [B,512,K] (row 511 pad)
    int* __restrict__ best_last)           // [B]
{
    const int b   = blockIdx.x;
    const int tid = threadIdx.x;
    const int j   = tid & 63;
    // wave id, forced uniform so readlane indices are SGPRs
    const int w   = __builtin_amdgcn_readfirstlane(tid >> 6);
    const int iwb = w * IW;

    __shared__ float vbuf[2][NW][KK];
    __shared__ int   ibuf[2][NW][KK];

    // this wave's slice of transitions: tc[q] = trans[iwb+q][j]
    float tc[IW];
#pragma unroll
    for (int q = 0; q < IW; ++q) tc[q] = trans[(iwb + q) * KK + j];

    const float* eb = emissions + (size_t)b * TT * KK;
    const int*   mb = attn_mask + (size_t)b * TT;
    unsigned char* hb = hist + (size_t)b * TT * KK;

    // every wave keeps a full (identical) copy of the score vector
    float score = start_t[j] + eb[j];

    // 2-deep prefetch rings
    float e0 = eb[KK + j];
    float e1 = eb[2 * KK + j];
    int   m0 = mb[1];
    int   m1 = mb[2];

    for (int t = 1; t < TT; ++t) {
        float e = e0; e0 = e1;
        int   m = m0; m0 = m1;
        int tn = (t + 2 < TT) ? (t + 2) : (TT - 1);
        e1 = eb[(size_t)tn * KK + j];
        m1 = mb[tn];

        // partial argmax over this wave's 16 prev-tags; 2 strict-> chains
        // (ascending i), merged low-chain-first => first-index tie rule.
        float b0 = NEG_INF, b1 = NEG_INF;
        int   i0 = iwb,     i1 = iwb + 8;
#pragma unroll
        for (int q = 0; q < 8; ++q) {
            float s0 = __uint_as_float(
                __builtin_amdgcn_readlane(__float_as_uint(score), iwb + q));
            float c0 = (s0 + tc[q]) + e;
            if (c0 > b0) { b0 = c0; i0 = iwb + q; }

            float s1 = __uint_as_float(
                __builtin_amdgcn_readlane(__float_as_uint(score), iwb + 8 + q));
            float c1 = (s1 + tc[8 + q]) + e;
            if (c1 > b1) { b1 = c1; i1 = iwb + 8 + q; }
        }
        float bw = b0; int iw_ = i0;
        if (b1 > bw) { bw = b1; iw_ = i1; }

        // cross-wave merge via double-buffered LDS (1 barrier per step)
        const int p = t & 1;
        vbuf[p][w][j] = bw;
        ibuf[p][w][j] = iw_;
        __syncthreads();

        float best = vbuf[p][0][j]; int bi = ibuf[p][0][j];
        {
            float v = vbuf[p][1][j]; int q_ = ibuf[p][1][j];
            if (v > best) { best = v; bi = q_; }
            v = vbuf[p][2][j]; q_ = ibuf[p][2][j];
            if (v > best) { best = v; bi = q_; }
            v = vbuf[p][3][j]; q_ = ibuf[p][3][j];
            if (v > best) { best = v; bi = q_; }
        }

        if (w == 0) hb[(size_t)(t - 1) * KK + j] = (unsigned char)bi;
        score = m ? best : score;   // freeze past sequence end (all waves identical)
    }

    float fin = score + end_t[j];
    __syncthreads();
    if (w == 0) vbuf[0][0][j] = fin;
    __syncthreads();
    if (tid == 0) {
        float bv = vbuf[0][0][0]; int bt = 0;
#pragma unroll
        for (int k = 1; k < KK; ++k) {
            float v = vbuf[0][0][k];
            if (v > bv) { bv = v; bt = k; }
        }
        best_last[b] = bt;
    }
}

__global__ __launch_bounds__(64) void viterbi_bt(
    const unsigned char* __restrict__ hist,  // [B,512,K]
    const int* __restrict__ attn_mask,       // [B,T]
    const int* __restrict__ best_last,       // [B]
    int* __restrict__ out)                   // [B,T] int32
{
    const int b = blockIdx.x;
    const int l = threadIdx.x;
    __shared__ int path[TT];

    const unsigned int* hw = (const unsigned int*)(hist + (size_t)b * TT * KK);
    const int* mb = attn_mask + (size_t)b * TT;

    int tag = best_last[b];          // broadcast (uniform on all lanes)
    if (l == 0) path[TT - 1] = tag;

    unsigned int dwA[16], dwB[16];
    int mA, mB;

    auto loadChunk = [&](int c, unsigned int (&dw)[16], int& mreg) {
#pragma unroll
        for (int q4 = 0; q4 < 16; ++q4)
            dw[q4] = hw[c * 1024 + q4 * 64 + l];   // 4 rows per wave-load
        int midx = c * 64 + l + 1;
        if (midx > TT - 1) midx = TT - 1;
        mreg = mb[midx];                            // lane l: mask[b][c*64+l+1]
    };
    auto procChunk = [&](int c, unsigned int (&dw)[16], int mreg) {
#pragma unroll
        for (int q = 63; q >= 0; --q) {
            int r = c * 64 + q;
            if (r < TT - 1) {
                // byte hist[r][tag]: local dword q*16+(tag>>2)
                unsigned int d = __shfl(dw[q >> 2], ((q & 3) << 4) + (tag >> 2));
                int pv = (int)((d >> ((tag & 3) << 3)) & 0xFFu);
                int m  = __shfl(mreg, q);
                tag = m ? pv : tag;
                if (l == 0) path[r] = tag;
            }
        }
    };

    loadChunk(7, dwA, mA);
    for (int c = 7; c >= 1; c -= 2) {
        loadChunk(c - 1, dwB, mB);
        procChunk(c, dwA, mA);
        if (c >= 2) loadChunk(c - 2, dwA, mA);
        procChunk(c - 1, dwB, mB);
    }

    __syncthreads();
#pragma unroll
    for (int cc = 0; cc < 8; ++cc)
        out[(size_t)b * TT + cc * 64 + l] = path[cc * 64 + l];
}

extern "C" void kernel_launch(void* const* d_in, const int* in_sizes, int n_in,
                              void* d_out, int out_size, void* d_ws, size_t ws_size,
                              hipStream_t stream) {
    const float* emissions = (const float*)d_in[0];
    const int* attn_mask   = (const int*)d_in[1];
    const float* start_t   = (const float*)d_in[2];
    const float* end_t     = (const float*)d_in[3];
    const float* trans     = (const float*)d_in[4];
    int* out = (int*)d_out;

    unsigned char* hist = (unsigned char*)d_ws;
    int* best_last = (int*)((char*)d_ws + (size_t)BB * TT * KK);

    viterbi_fwd<<<BB, NW * KK, 0, stream>>>(emissions, attn_mask, start_t, end_t,
                                            trans, hist, best_last);
    viterbi_bt<<<BB, KK, 0, stream>>>(hist, attn_mask, best_last, out);
}